// Round 9
// baseline (455.941 us; speedup 1.0000x reference)
//
#include <hip/hip_runtime.h>
#include <hip/hip_cooperative_groups.h>

namespace cg = cooperative_groups;

typedef unsigned int u32;
typedef unsigned short u16;
typedef __attribute__((ext_vector_type(8))) short short8;
typedef __attribute__((ext_vector_type(4))) float f32x4;

#define DEV static __device__ __forceinline__

DEV float b2f(u16 v){ union{u32 u; float f;} c; c.u = ((u32)v) << 16; return c.f; }
DEV u16 f2b(float f){ union{float ff; u32 u;} c; c.ff = f; return (u16)((c.u + 0x7fffu + ((c.u >> 16) & 1u)) >> 16); }
DEV float sigm(float x){ return 1.f/(1.f + __expf(-x)); }
DEV float tanh_(float x){ float e = __expf(-2.f*x); return (1.f-e)/(1.f+e); }

// dims: B=64, T=64, P=32, H=256, 3H=768.
// Packed B in ws: per series: 48 N-tiles x 9 K-tiles x 64 lanes x 8 bf16.
#define SER_STRIDE 221184   // u16 per series

// LDS: Blds (K6,K7,K8: 48nt x 3 x 1KB) | hA (2 parities x 2048 u16)
//      | xA (2 parities x 256 u16) | lwfc (256 u16)
#define BLDS_U16 (48*3*64*8)
#define HA_U16   (2*2048)
#define XAB_U16  (2*256)
#define LWF_U16  256
#define SMEM_BYTES ((BLDS_U16 + HA_U16 + XAB_U16 + LWF_U16)*2)

// element (m in 0..7, c in 0..255) -> u16 index within one hA parity
DEV int hxi(int m, int c){ return (((c>>5)*32) + (((c>>3)&3)*8) + m)*8 + (c&7); }

// pack one fragment f (n0*9+k) of one series into packed layout
DEV void pack_one(const float* __restrict__ Wih, const float* __restrict__ Whh,
                  int f, int lane, u16* __restrict__ dstSer)
{
  const int n0 = f / 9, k = f - n0*9;
  const int n = lane & 15, q = lane >> 4;
  const int row = n0*16 + n;
  const float* src = (k < 8) ? (Whh + row*256 + k*32 + q*8) : (Wih + row*32 + q*8);
  u32 wd[4];
  #pragma unroll
  for (int j = 0; j < 4; ++j) {
    u16 lo = f2b(src[2*j]);
    u16 hi = f2b(src[2*j+1]);
    wd[j] = (u32)lo | ((u32)hi << 16);
  }
  *(uint4*)(dstSer + ((size_t)f*64 + lane)*8) = make_uint4(wd[0], wd[1], wd[2], wd[3]);
}

// stage Blds (K6,K7,K8 for all 48 ntiles) + Bres (K0..5 for this wave) from packed ws
DEV void stage_weights(const u16* __restrict__ Bp, u16* Blds, short8* Bres, int tid)
{
  const int w = tid >> 6, lane = tid & 63;
  #pragma unroll
  for (int r = 0; r < 18; ++r) {
    const int g = r*512 + tid;     // 0..9215 uint4s
    const int frag = g >> 6, e = g & 63;
    const int nt = frag / 3, kk = frag - nt*3;
    ((uint4*)Blds)[g] = ((const uint4*)Bp)[((size_t)nt*9 + 6 + kk)*64 + e];
  }
  #pragma unroll
  for (int i = 0; i < 2; ++i)
    #pragma unroll
    for (int g = 0; g < 3; ++g)
      #pragma unroll
      for (int k = 0; k < 6; ++k)
        Bres[(i*3+g)*6 + k] =
          *(const short8*)(Bp + (((size_t)(g*16 + 2*w + i)*9 + k)*64 + lane)*8);
  #pragma unroll
  for (int r = 0; r < 36; ++r)
    asm volatile("" : "+v"(Bres[r]));
}

// ============ GRU run: 512 thr = 8 waves, M=8 batches, N=768 gate rows ============
// weights pre-staged (Blds in LDS, Bres in regs). One barrier/step (h parity dbuf).
template<int NSTEPS, bool IS_DEC>
DEV void gru_run(u16* hA, u16* xA, u16* lwfc, u16* Blds, const short8* Bres,
                 const float* __restrict__ bihP, const float* __restrict__ bhhP,
                 const float* __restrict__ X, const float* __restrict__ z0,
                 const float* __restrict__ lwp, const float* __restrict__ lbp,
                 float* __restrict__ predp, int b0)
{
  const int tid = threadIdx.x;
  const int w = tid >> 6, lane = tid & 63;
  const int n = lane & 15, q = lane >> 4;
  const int isel  = q >> 1;
  const int mbase = (q & 1) * 4;
  const int colS  = (2*w + isel)*16 + n;

  // zero hA parity0 + xA parity0
  ((u32*)hA)[tid] = 0; ((u32*)hA)[tid + 512] = 0;
  if (tid < 128) ((u32*)xA)[tid] = 0;
  __syncthreads();

  if (IS_DEC) {                    // h(0) = z into parity 0 (bf16 frag-packed)
    const int m = tid >> 6, c0 = (tid*4) & 255;
    float4 v = *(const float4*)&z0[(b0+m)*256 + c0];
    const int base = hxi(m, c0);
    hA[base]   = f2b(v.x); hA[base+1] = f2b(v.y);
    hA[base+2] = f2b(v.z); hA[base+3] = f2b(v.w);
    if (tid < 256) lwfc[tid] = f2b(lwp[tid]);
  } else if (tid < 256) {          // x(0) into parity 0
    const int m = tid >> 5, c = tid & 31;
    xA[((c>>3)*8 + m)*8 + (c&7)] = f2b(X[(b0+m)*2048 + c]);
  }

  const float brS  = bihP[colS]     + bhhP[colS];
  const float bzS  = bihP[256+colS] + bhhP[256+colS];
  const float bnxS = bihP[512+colS];
  const float bnhS = bhhP[512+colS];
  const float lb = IS_DEC ? lbp[0] : 0.f;

  float hold[4];
  #pragma unroll
  for (int rr = 0; rr < 4; ++rr)
    hold[rr] = IS_DEC ? b2f(f2b(z0[(b0 + mbase + rr)*256 + colS])) : 0.f;

  const int wbase = hxi(mbase, colS);
  __syncthreads();

  #pragma unroll 1
  for (int t = 0; t < NSTEPS; ++t) {
    const int par = t & 1;
    u16* hP = hA + par*2048;

    float xv = 0.f;
    const bool doX = (t+1 < NSTEPS) && (tid < 256);
    const int xm = tid >> 5, xc = tid & 31;
    if (doX) xv = X[(b0+xm)*2048 + (IS_DEC ? (t+10) : (t+1))*32 + xc];

    short8 af[9];
    #pragma unroll
    for (int k0 = 0; k0 < 8; ++k0)
      af[k0] = *(const short8*)&hP[(k0*32 + q*8 + (n&7))*8];
    af[8] = *(const short8*)&xA[par*256 + (q*8 + (n&7))*8];

    if (IS_DEC && w == 0 && t > 0) {
      f32x4 lp = {0,0,0,0};
      #pragma unroll
      for (int k0 = 0; k0 < 8; ++k0) {
        const short8 lf = *(const short8*)&lwfc[(k0*4 + q)*8];
        lp = __builtin_amdgcn_mfma_f32_16x16x32_bf16(af[k0], lf, lp, 0,0,0);
      }
      if (n == 0 && q < 2) {
        #pragma unroll
        for (int rr = 0; rr < 4; ++rr)
          predp[(b0 + q*4 + rr)*54 + (t-1)] = lp[rr] + lb;
      }
    }

    if (doX) xA[(par^1)*256 + ((xc>>3)*8 + xm)*8 + (xc&7)] = f2b(xv);

    f32x4 accr[2], accz[2], accnh[2], accnx[2];
    #pragma unroll
    for (int i = 0; i < 2; ++i) {
      const int ntr = 2*w + i, ntz = 16 + 2*w + i, ntn = 32 + 2*w + i;
      f32x4 ar={0,0,0,0}, az={0,0,0,0}, anh={0,0,0,0}, anx={0,0,0,0};
      const short8 b6r = *(const short8*)&Blds[((ntr*3+0)*64+lane)*8];
      const short8 b7r = *(const short8*)&Blds[((ntr*3+1)*64+lane)*8];
      const short8 b8r = *(const short8*)&Blds[((ntr*3+2)*64+lane)*8];
      const short8 b6z = *(const short8*)&Blds[((ntz*3+0)*64+lane)*8];
      const short8 b7z = *(const short8*)&Blds[((ntz*3+1)*64+lane)*8];
      const short8 b8z = *(const short8*)&Blds[((ntz*3+2)*64+lane)*8];
      const short8 b6n = *(const short8*)&Blds[((ntn*3+0)*64+lane)*8];
      const short8 b7n = *(const short8*)&Blds[((ntn*3+1)*64+lane)*8];
      const short8 b8n = *(const short8*)&Blds[((ntn*3+2)*64+lane)*8];
      #pragma unroll
      for (int k = 0; k < 6; ++k) {
        ar  = __builtin_amdgcn_mfma_f32_16x16x32_bf16(af[k], Bres[(i*3+0)*6+k], ar, 0,0,0);
        az  = __builtin_amdgcn_mfma_f32_16x16x32_bf16(af[k], Bres[(i*3+1)*6+k], az, 0,0,0);
        anh = __builtin_amdgcn_mfma_f32_16x16x32_bf16(af[k], Bres[(i*3+2)*6+k], anh, 0,0,0);
      }
      ar  = __builtin_amdgcn_mfma_f32_16x16x32_bf16(af[6], b6r, ar, 0,0,0);
      ar  = __builtin_amdgcn_mfma_f32_16x16x32_bf16(af[7], b7r, ar, 0,0,0);
      ar  = __builtin_amdgcn_mfma_f32_16x16x32_bf16(af[8], b8r, ar, 0,0,0);
      az  = __builtin_amdgcn_mfma_f32_16x16x32_bf16(af[6], b6z, az, 0,0,0);
      az  = __builtin_amdgcn_mfma_f32_16x16x32_bf16(af[7], b7z, az, 0,0,0);
      az  = __builtin_amdgcn_mfma_f32_16x16x32_bf16(af[8], b8z, az, 0,0,0);
      anh = __builtin_amdgcn_mfma_f32_16x16x32_bf16(af[6], b6n, anh, 0,0,0);
      anh = __builtin_amdgcn_mfma_f32_16x16x32_bf16(af[7], b7n, anh, 0,0,0);
      anx = __builtin_amdgcn_mfma_f32_16x16x32_bf16(af[8], b8n, anx, 0,0,0);
      accr[i] = ar; accz[i] = az; accnh[i] = anh; accnx[i] = anx;
    }

    u16* hW = hA + (par^1)*2048;
    #pragma unroll
    for (int rr = 0; rr < 4; ++rr) {
      const float r1  = __shfl_xor(accr[1][rr],  32, 64);
      const float z1  = __shfl_xor(accz[1][rr],  32, 64);
      const float nh1 = __shfl_xor(accnh[1][rr], 32, 64);
      const float nx1 = __shfl_xor(accnx[1][rr], 32, 64);
      const float arv  = (q >= 2) ? r1  : accr[0][rr];
      const float azv  = (q >= 2) ? z1  : accz[0][rr];
      const float anhv = (q >= 2) ? nh1 : accnh[0][rr];
      const float anxv = (q >= 2) ? nx1 : accnx[0][rr];
      const float rg = sigm(arv + brS);
      const float zg = sigm(azv + bzS);
      const float nv = tanh_(anxv + bnxS + rg*(anhv + bnhS));
      const float hn = (1.f - zg)*nv + zg*hold[rr];
      const u16 hb = f2b(hn);
      hold[rr] = b2f(hb);
      hW[wbase + rr*8] = hb;
    }
    __syncthreads();
  }

  if (IS_DEC && w == 0) {
    const u16* hF = hA + (NSTEPS&1)*2048;
    f32x4 lp = {0,0,0,0};
    #pragma unroll
    for (int k0 = 0; k0 < 8; ++k0) {
      const short8 a = *(const short8*)&hF[(k0*32 + q*8 + (n&7))*8];
      const short8 lf = *(const short8*)&lwfc[(k0*4 + q)*8];
      lp = __builtin_amdgcn_mfma_f32_16x16x32_bf16(a, lf, lp, 0,0,0);
    }
    if (n == 0 && q < 2) {
      #pragma unroll
      for (int rr = 0; rr < 4; ++rr)
        predp[(b0 + q*4 + rr)*54 + (NSTEPS-1)] = lp[rr] + lb;
    }
  }
}

DEV void latent(const u16* hA,
                const float* __restrict__ Wmu, const float* __restrict__ bmu,
                const float* __restrict__ Wsd, const float* __restrict__ bsd,
                const float* __restrict__ eps,
                float* __restrict__ z, float* __restrict__ out_lv,
                float* __restrict__ out_mu, int b0, int tid)
{
  const int j = tid & 255, half = tid >> 8;
  float am[4] = {0,0,0,0}, as[4] = {0,0,0,0};
  const float* wmrow = Wmu + j*256;
  const float* wsrow = Wsd + j*256;
  const u16* hF = hA;                          // final parity 0 for NSTEPS=10
  #pragma unroll 2
  for (int c0 = 0; c0 < 256; c0 += 8) {
    float4 wm0 = *(const float4*)&wmrow[c0];
    float4 wm1 = *(const float4*)&wmrow[c0+4];
    float4 ws0 = *(const float4*)&wsrow[c0];
    float4 ws1 = *(const float4*)&wsrow[c0+4];
    #pragma unroll
    for (int mm = 0; mm < 4; ++mm) {
      const u16* hp = &hF[hxi(half*4 + mm, c0)];
      float h0x=b2f(hp[0]), h0y=b2f(hp[1]), h0z=b2f(hp[2]), h0w=b2f(hp[3]);
      float h1x=b2f(hp[4]), h1y=b2f(hp[5]), h1z=b2f(hp[6]), h1w=b2f(hp[7]);
      am[mm] += wm0.x*h0x + wm0.y*h0y + wm0.z*h0z + wm0.w*h0w
              + wm1.x*h1x + wm1.y*h1y + wm1.z*h1z + wm1.w*h1w;
      as[mm] += ws0.x*h0x + ws0.y*h0y + ws0.z*h0z + ws0.w*h0w
              + ws1.x*h1x + ws1.y*h1y + ws1.z*h1z + ws1.w*h1w;
    }
  }
  #pragma unroll
  for (int mm = 0; mm < 4; ++mm) {
    const int b = b0 + half*4 + mm;
    const float mu = am[mm] + bmu[j];
    const float lv = as[mm] + bsd[j];
    const float zv = mu + __expf(0.5f*lv) * eps[b*256 + j];
    z[b*256 + j]      = zv;
    out_lv[b*256 + j] = lv;
    out_mu[b*256 + j] = mu;
  }
}

// ===================== fused cooperative kernel =====================
// grid 256 WGs (1/CU): gid = p + 32*s. Phase1: distributed pack. sync.
// Phase2: gid<8 -> encoder+latent; others pre-stage dec weights. sync.
// Phase3: all run 54-step decoder.
__global__ __launch_bounds__(512, 2) void fused(
    const float* __restrict__ X, const float* __restrict__ eps,
    const float* __restrict__ WihE, const float* __restrict__ WhhE,
    const float* __restrict__ bihE, const float* __restrict__ bhhE,
    const float* __restrict__ Wmu, const float* __restrict__ bmu,
    const float* __restrict__ Wsd, const float* __restrict__ bsd,
    const float* __restrict__ WihD, const float* __restrict__ WhhD,
    const float* __restrict__ bihD, const float* __restrict__ bhhD,
    const float* __restrict__ lin_w, const float* __restrict__ lin_b,
    u16* __restrict__ wsB, float* __restrict__ z,
    float* __restrict__ pred, float* __restrict__ out_lv, float* __restrict__ out_mu)
{
  extern __shared__ char smem[];
  u16* Blds = (u16*)smem;
  u16* hA   = Blds + BLDS_U16;
  u16* xA   = hA + HA_U16;
  u16* lwfc = xA + XAB_U16;
  const int gid = blockIdx.x;
  const int p = gid & 31, s = gid >> 5, b0 = s*8;
  const int tid = threadIdx.x;

  // phase 1: distributed pack (series p frags s*54..s*54+53; enc series by gid>=248)
  {
    const int fbase = s*54;
    u16* dst = wsB + (size_t)p*SER_STRIDE;
    const float* Wih = WihD + p*24576;
    const float* Whh = WhhD + p*196608;
    for (int it = tid; it < 54*64; it += 512)
      pack_one(Wih, Whh, fbase + (it>>6), it & 63, dst);
    if (gid >= 248) {
      const int fb2 = (gid - 248)*54;
      u16* dstE = wsB + (size_t)32*SER_STRIDE;
      for (int it = tid; it < 54*64; it += 512)
        pack_one(WihE, WhhE, fb2 + (it>>6), it & 63, dstE);
    }
  }
  __threadfence();
  cg::this_grid().sync();

  short8 Bres[36];
  if (gid < 8) {
    stage_weights(wsB + (size_t)32*SER_STRIDE, Blds, Bres, tid);
    gru_run<10, false>(hA, xA, lwfc, Blds, Bres, bihE, bhhE, X,
                       nullptr, nullptr, nullptr, nullptr, gid*8);
    __syncthreads();
    latent(hA, Wmu, bmu, Wsd, bsd, eps, z, out_lv, out_mu, gid*8, tid);
  } else {
    stage_weights(wsB + (size_t)p*SER_STRIDE, Blds, Bres, tid);
  }
  __threadfence();
  cg::this_grid().sync();

  if (gid < 8)
    stage_weights(wsB + (size_t)p*SER_STRIDE, Blds, Bres, tid);

  gru_run<54, true>(hA, xA, lwfc, Blds, Bres,
                    bihD + p*768, bhhD + p*768, X, z,
                    lin_w + p*256, lin_b + p, pred + p*3456, b0);
}

extern "C" void kernel_launch(void* const* d_in, const int* in_sizes, int n_in,
                              void* d_out, int out_size, void* d_ws, size_t ws_size,
                              hipStream_t stream) {
  const float* X        = (const float*)d_in[0];
  const float* eps      = (const float*)d_in[1];
  const float* Wih_enc  = (const float*)d_in[2];
  const float* Whh_enc  = (const float*)d_in[3];
  const float* bih_enc  = (const float*)d_in[4];
  const float* bhh_enc  = (const float*)d_in[5];
  const float* fc_mu_w  = (const float*)d_in[6];
  const float* fc_mu_b  = (const float*)d_in[7];
  const float* fc_std_w = (const float*)d_in[8];
  const float* fc_std_b = (const float*)d_in[9];
  const float* Wih_dec  = (const float*)d_in[10];
  const float* Whh_dec  = (const float*)d_in[11];
  const float* bih_dec  = (const float*)d_in[12];
  const float* bhh_dec  = (const float*)d_in[13];
  const float* lin_w    = (const float*)d_in[14];
  const float* lin_b    = (const float*)d_in[15];

  float* out    = (float*)d_out;
  float* pred   = out;              // [32][64][54][1] = 110592
  float* out_lv = out + 110592;     // [1][64][256]
  float* out_mu = out + 126976;     // [1][64][256]

  u16*   wsB = (u16*)d_ws;                                       // 33 * 221184 u16
  float* z   = (float*)((char*)d_ws + (size_t)33*SER_STRIDE*2);  // [64][256] fp32

  (void)hipFuncSetAttribute((const void*)fused,
      hipFuncAttributeMaxDynamicSharedMemorySize, SMEM_BYTES);

  void* args[] = {
    (void*)&X, (void*)&eps,
    (void*)&Wih_enc, (void*)&Whh_enc, (void*)&bih_enc, (void*)&bhh_enc,
    (void*)&fc_mu_w, (void*)&fc_mu_b, (void*)&fc_std_w, (void*)&fc_std_b,
    (void*)&Wih_dec, (void*)&Whh_dec, (void*)&bih_dec, (void*)&bhh_dec,
    (void*)&lin_w, (void*)&lin_b,
    (void*)&wsB, (void*)&z, (void*)&pred, (void*)&out_lv, (void*)&out_mu
  };
  (void)hipLaunchCooperativeKernel((const void*)fused, dim3(256), dim3(512),
                                   args, SMEM_BYTES, stream);
}

// Round 10
// 292.795 us; speedup vs baseline: 1.5572x; 1.5572x over previous
//
#include <hip/hip_runtime.h>

typedef unsigned int u32;
typedef unsigned short u16;
typedef __attribute__((ext_vector_type(8))) short short8;
typedef __attribute__((ext_vector_type(4))) float f32x4;

#define DEV static __device__ __forceinline__

DEV float b2f(u16 v){ union{u32 u; float f;} c; c.u = ((u32)v) << 16; return c.f; }
DEV u16 f2b(float f){ union{float ff; u32 u;} c; c.ff = f; return (u16)((c.u + 0x7fffu + ((c.u >> 16) & 1u)) >> 16); }
DEV float sigm(float x){ return 1.f/(1.f + __expf(-x)); }
DEV float tanh_(float x){ float e = __expf(-2.f*x); return (1.f-e)/(1.f+e); }

// dims: B=64, T=64, P=32, H=256, 3H=768.
// Packed B in ws: per series: 48 N-tiles x 9 K-tiles x 64 lanes x 8 bf16.
#define SER_STRIDE 221184   // u16 per series

// LDS: Blds (K7,K8: 48nt x 2 x 1KB) | hA (2 parities x 2048 u16)
//      | xall (54 steps x 256 u16, staged once) | lwfc (256 u16)
#define BLDS_U16 (48*2*64*8)
#define HA_U16   (2*2048)
#define XALL_U16 (54*256)
#define LWF_U16  256
#define SMEM_BYTES ((BLDS_U16 + HA_U16 + XALL_U16 + LWF_U16)*2)

// element (m in 0..7, c in 0..255) -> u16 index within one hA parity
DEV int hxi(int m, int c){ return (((c>>5)*32) + (((c>>3)&3)*8) + m)*8 + (c&7); }

// ===================== fragment pack (fp32 -> bf16 frags, once) =====================
__global__ __launch_bounds__(256) void pack_kernel(
    const float* __restrict__ WihD, const float* __restrict__ WhhD,
    const float* __restrict__ WihE, const float* __restrict__ WhhE,
    u16* __restrict__ wsB)
{
  const int ps = blockIdx.y;           // 0..31 dec series, 32 = encoder
  const int f  = blockIdx.x*4 + (threadIdx.x >> 6);   // n0*9 + k, 0..431
  const int n0 = f / 9, k = f - n0*9;
  const int lane = threadIdx.x & 63;
  const int n = lane & 15, q = lane >> 4;
  const int row = n0*16 + n;
  const float* Whh = (ps < 32) ? WhhD + ps*196608 : WhhE;
  const float* Wih = (ps < 32) ? WihD + ps*24576  : WihE;
  const float* src = (k < 8) ? (Whh + row*256 + k*32 + q*8) : (Wih + row*32 + q*8);
  u32 wd[4];
  #pragma unroll
  for (int j = 0; j < 4; ++j) {
    u16 lo = f2b(src[2*j]);
    u16 hi = f2b(src[2*j+1]);
    wd[j] = (u32)lo | ((u32)hi << 16);
  }
  *(uint4*)(wsB + (((size_t)ps*432 + f)*64 + lane)*8) = make_uint4(wd[0], wd[1], wd[2], wd[3]);
}

// ============ GRU body: 512 thr = 8 waves, M=8 batches, N=768 gate rows ============
// wave w owns hidden cols [32w, 32w+32) = col-tiles {2w, 2w+1}.
// B: K0..6 VGPR-resident (42 frags, packed loads + asm pin); K7,K8 in LDS.
// x for all steps staged in LDS once. One barrier/step (h parity dbuf).
template<int NSTEPS, bool IS_DEC>
DEV void gru_body(u16* hA, u16* xall, u16* Blds, u16* lwfc,
                  const u16* __restrict__ Bp,
                  const float* __restrict__ bihP, const float* __restrict__ bhhP,
                  const float* __restrict__ X, const float* __restrict__ z0,
                  const float* __restrict__ lwp, const float* __restrict__ lbp,
                  float* __restrict__ predp, int b0)
{
  const int tid = threadIdx.x;
  const int w = tid >> 6, lane = tid & 63;
  const int n = lane & 15, q = lane >> 4;
  const int isel  = q >> 1;
  const int mbase = (q & 1) * 4;
  const int colS  = (2*w + isel)*16 + n;

  // zero h parity 0 (enc path needs it; dec overwrites fully with z)
  ((u32*)hA)[tid] = 0; ((u32*)hA)[tid + 512] = 0;
  __syncthreads();

  if (IS_DEC) {                    // h(0) = z into parity 0 (bf16 frag-packed)
    const int m = tid >> 6, c0 = (tid*4) & 255;
    float4 v = *(const float4*)&z0[(b0+m)*256 + c0];
    const int base = hxi(m, c0);
    hA[base]   = f2b(v.x); hA[base+1] = f2b(v.y);
    hA[base+2] = f2b(v.z); hA[base+3] = f2b(v.w);
    if (tid < 256) lwfc[tid] = f2b(lwp[tid]);
  }

  // stage x for ALL steps into LDS (A-frag order per step)
  for (int idx = tid; idx < NSTEPS*256; idx += 512) {
    const int t = idx >> 8, r = idx & 255;
    const int c = ((r >> 6) << 3) | (r & 7);
    const int m = (r >> 3) & 7;
    float v;
    if (IS_DEC) v = (t == 0) ? 0.f : X[(b0+m)*2048 + (t+9)*32 + c];
    else        v = X[(b0+m)*2048 + t*32 + c];
    xall[idx] = f2b(v);
  }

  // stage Blds: K7,K8 frags for all 48 ntiles — pure uint4 copies
  #pragma unroll
  for (int r = 0; r < 12; ++r) {
    const int g = r*512 + tid;     // 0..6143 uint4s
    const int frag = g >> 6, e = g & 63;
    const int nt = frag >> 1, kk = frag & 1;
    ((uint4*)Blds)[g] = ((const uint4*)Bp)[((size_t)nt*9 + 7 + kk)*64 + e];
  }

  // resident B: K0..6 for wave's 6 N-tiles — pure short8 loads + pin
  short8 Bres[42];
  #pragma unroll
  for (int i = 0; i < 2; ++i)
    #pragma unroll
    for (int g = 0; g < 3; ++g)
      #pragma unroll
      for (int k = 0; k < 7; ++k)
        Bres[(i*3+g)*7 + k] =
          *(const short8*)(Bp + (((size_t)(g*16 + 2*w + i)*9 + k)*64 + lane)*8);
  #pragma unroll
  for (int r = 0; r < 42; ++r)
    asm volatile("" : "+v"(Bres[r]));

  const float brS  = bihP[colS]     + bhhP[colS];
  const float bzS  = bihP[256+colS] + bhhP[256+colS];
  const float bnxS = bihP[512+colS];
  const float bnhS = bhhP[512+colS];
  const float lb = IS_DEC ? lbp[0] : 0.f;

  float hold[4];
  #pragma unroll
  for (int rr = 0; rr < 4; ++rr)
    hold[rr] = IS_DEC ? b2f(f2b(z0[(b0 + mbase + rr)*256 + colS])) : 0.f;

  const int wbase = hxi(mbase, colS);
  const int nt0 = 2*w,      nt1 = 2*w + 1;        // r N-tiles for i=0,1
  __syncthreads();

  #pragma unroll 1
  for (int t = 0; t < NSTEPS; ++t) {
    const int par = t & 1;
    const u16* hP = hA + par*2048;
    const int arow = (q*8 + (n&7))*8;

    f32x4 ar0={0,0,0,0}, az0={0,0,0,0}, anh0={0,0,0,0}, anx0={0,0,0,0};
    f32x4 ar1={0,0,0,0}, az1={0,0,0,0}, anh1={0,0,0,0}, anx1={0,0,0,0};
    f32x4 lp ={0,0,0,0};
    const bool doLin = IS_DEC && (w == 0) && (t > 0);

    // K0..6: A-frag per k from LDS, B from registers
    #pragma unroll
    for (int k = 0; k < 7; ++k) {
      const short8 a = *(const short8*)&hP[(k*32)*8 + arow];
      ar0  = __builtin_amdgcn_mfma_f32_16x16x32_bf16(a, Bres[0*7+k],  ar0, 0,0,0);
      az0  = __builtin_amdgcn_mfma_f32_16x16x32_bf16(a, Bres[1*7+k],  az0, 0,0,0);
      anh0 = __builtin_amdgcn_mfma_f32_16x16x32_bf16(a, Bres[2*7+k],  anh0,0,0,0);
      ar1  = __builtin_amdgcn_mfma_f32_16x16x32_bf16(a, Bres[3*7+k],  ar1, 0,0,0);
      az1  = __builtin_amdgcn_mfma_f32_16x16x32_bf16(a, Bres[4*7+k],  az1, 0,0,0);
      anh1 = __builtin_amdgcn_mfma_f32_16x16x32_bf16(a, Bres[5*7+k],  anh1,0,0,0);
      if (doLin) {
        const short8 lf = *(const short8*)&lwfc[(k*4 + q)*8];
        lp = __builtin_amdgcn_mfma_f32_16x16x32_bf16(a, lf, lp, 0,0,0);
      }
    }
    // K7: A-frag from LDS, B from Blds
    {
      const short8 a = *(const short8*)&hP[(7*32)*8 + arow];
      #pragma unroll
      for (int i = 0; i < 2; ++i) {
        const int nti = 2*w + i;
        const short8 b7r = *(const short8*)&Blds[(((nti     )*2+0)*64+lane)*8];
        const short8 b7z = *(const short8*)&Blds[(((16+nti  )*2+0)*64+lane)*8];
        const short8 b7n = *(const short8*)&Blds[(((32+nti  )*2+0)*64+lane)*8];
        if (i == 0) {
          ar0  = __builtin_amdgcn_mfma_f32_16x16x32_bf16(a, b7r, ar0, 0,0,0);
          az0  = __builtin_amdgcn_mfma_f32_16x16x32_bf16(a, b7z, az0, 0,0,0);
          anh0 = __builtin_amdgcn_mfma_f32_16x16x32_bf16(a, b7n, anh0,0,0,0);
        } else {
          ar1  = __builtin_amdgcn_mfma_f32_16x16x32_bf16(a, b7r, ar1, 0,0,0);
          az1  = __builtin_amdgcn_mfma_f32_16x16x32_bf16(a, b7z, az1, 0,0,0);
          anh1 = __builtin_amdgcn_mfma_f32_16x16x32_bf16(a, b7n, anh1,0,0,0);
        }
      }
      if (doLin) {
        const short8 lf = *(const short8*)&lwfc[(7*4 + q)*8];
        lp = __builtin_amdgcn_mfma_f32_16x16x32_bf16(a, lf, lp, 0,0,0);
      }
    }
    // K8 (x): A-frag from xall, B from Blds; n-gate goes to separate anx
    {
      const short8 a = *(const short8*)&xall[t*256 + arow];
      #pragma unroll
      for (int i = 0; i < 2; ++i) {
        const int nti = 2*w + i;
        const short8 b8r = *(const short8*)&Blds[(((nti     )*2+1)*64+lane)*8];
        const short8 b8z = *(const short8*)&Blds[(((16+nti  )*2+1)*64+lane)*8];
        const short8 b8n = *(const short8*)&Blds[(((32+nti  )*2+1)*64+lane)*8];
        if (i == 0) {
          ar0  = __builtin_amdgcn_mfma_f32_16x16x32_bf16(a, b8r, ar0, 0,0,0);
          az0  = __builtin_amdgcn_mfma_f32_16x16x32_bf16(a, b8z, az0, 0,0,0);
          anx0 = __builtin_amdgcn_mfma_f32_16x16x32_bf16(a, b8n, anx0,0,0,0);
        } else {
          ar1  = __builtin_amdgcn_mfma_f32_16x16x32_bf16(a, b8r, ar1, 0,0,0);
          az1  = __builtin_amdgcn_mfma_f32_16x16x32_bf16(a, b8z, az1, 0,0,0);
          anx1 = __builtin_amdgcn_mfma_f32_16x16x32_bf16(a, b8n, anx1,0,0,0);
        }
      }
    }

    if (doLin && n == 0 && q < 2) {
      #pragma unroll
      for (int rr = 0; rr < 4; ++rr)
        predp[(b0 + q*4 + rr)*54 + (t-1)] = lp[rr] + lb;
    }

    // epilogue: shfl_xor(32) redistributes i=1 rows to lanes q>=2
    u16* hW = hA + (par^1)*2048;
    #pragma unroll
    for (int rr = 0; rr < 4; ++rr) {
      const float r1  = __shfl_xor(ar1[rr],  32, 64);
      const float z1  = __shfl_xor(az1[rr],  32, 64);
      const float nh1 = __shfl_xor(anh1[rr], 32, 64);
      const float nx1 = __shfl_xor(anx1[rr], 32, 64);
      const float arv  = (q >= 2) ? r1  : ar0[rr];
      const float azv  = (q >= 2) ? z1  : az0[rr];
      const float anhv = (q >= 2) ? nh1 : anh0[rr];
      const float anxv = (q >= 2) ? nx1 : anx0[rr];
      const float rg = sigm(arv + brS);
      const float zg = sigm(azv + bzS);
      const float nv = tanh_(anxv + bnxS + rg*(anhv + bnhS));
      const float hn = nv + zg*(hold[rr] - nv);
      const u16 hb = f2b(hn);
      hold[rr] = b2f(hb);
      hW[wbase + rr*8] = hb;
    }
    __syncthreads();               // writes(par^1) visible, reads(par) done
  }

  // tail: pred(NSTEPS-1) from final h (parity NSTEPS&1)
  if (IS_DEC && w == 0) {
    const u16* hF = hA + (NSTEPS&1)*2048;
    f32x4 lp = {0,0,0,0};
    #pragma unroll
    for (int k0 = 0; k0 < 8; ++k0) {
      const short8 a = *(const short8*)&hF[(k0*32 + q*8 + (n&7))*8];
      const short8 lf = *(const short8*)&lwfc[(k0*4 + q)*8];
      lp = __builtin_amdgcn_mfma_f32_16x16x32_bf16(a, lf, lp, 0,0,0);
    }
    if (n == 0 && q < 2) {
      #pragma unroll
      for (int rr = 0; rr < 4; ++rr)
        predp[(b0 + q*4 + rr)*54 + (NSTEPS-1)] = lp[rr] + lb;
    }
  }
}

// ===================== encoder + latent (fused) =====================
__global__ __launch_bounds__(512, 2) void enc_lat(
    const u16* __restrict__ wsB,
    const float* __restrict__ bih, const float* __restrict__ bhh,
    const float* __restrict__ X,
    const float* __restrict__ Wmu, const float* __restrict__ bmu,
    const float* __restrict__ Wsd, const float* __restrict__ bsd,
    const float* __restrict__ eps,
    float* __restrict__ z, float* __restrict__ out_lv, float* __restrict__ out_mu)
{
  extern __shared__ char smem[];
  u16* Blds = (u16*)smem;
  u16* hA   = Blds + BLDS_U16;
  u16* xall = hA + HA_U16;
  u16* lwfc = xall + XALL_U16;
  const int b0 = blockIdx.y * 8;
  gru_body<10, false>(hA, xall, Blds, lwfc, wsB + (size_t)32*SER_STRIDE,
                      bih, bhh, X, nullptr, nullptr, nullptr, nullptr, b0);
  __syncthreads();
  // latent from final h (parity 0 for NSTEPS=10)
  const int tid = threadIdx.x;
  const int j = tid & 255, half = tid >> 8;
  float am[4] = {0,0,0,0}, as[4] = {0,0,0,0};
  const float* wmrow = Wmu + j*256;
  const float* wsrow = Wsd + j*256;
  const u16* hF = hA;
  #pragma unroll 2
  for (int c0 = 0; c0 < 256; c0 += 8) {
    float4 wm0 = *(const float4*)&wmrow[c0];
    float4 wm1 = *(const float4*)&wmrow[c0+4];
    float4 ws0 = *(const float4*)&wsrow[c0];
    float4 ws1 = *(const float4*)&wsrow[c0+4];
    #pragma unroll
    for (int mm = 0; mm < 4; ++mm) {
      const u16* hp = &hF[hxi(half*4 + mm, c0)];
      float h0x=b2f(hp[0]), h0y=b2f(hp[1]), h0z=b2f(hp[2]), h0w=b2f(hp[3]);
      float h1x=b2f(hp[4]), h1y=b2f(hp[5]), h1z=b2f(hp[6]), h1w=b2f(hp[7]);
      am[mm] += wm0.x*h0x + wm0.y*h0y + wm0.z*h0z + wm0.w*h0w
              + wm1.x*h1x + wm1.y*h1y + wm1.z*h1z + wm1.w*h1w;
      as[mm] += ws0.x*h0x + ws0.y*h0y + ws0.z*h0z + ws0.w*h0w
              + ws1.x*h1x + ws1.y*h1y + ws1.z*h1z + ws1.w*h1w;
    }
  }
  #pragma unroll
  for (int mm = 0; mm < 4; ++mm) {
    const int b = b0 + half*4 + mm;
    const float mu = am[mm] + bmu[j];
    const float lv = as[mm] + bsd[j];
    const float zv = mu + __expf(0.5f*lv) * eps[b*256 + j];
    z[b*256 + j]      = zv;
    out_lv[b*256 + j] = lv;
    out_mu[b*256 + j] = mu;
  }
}

// ===================== decoder =====================
// grid (32 series, 8 batch-slices): linear id = p + 32*s -> XCD = p%8 (L2 locality)
__global__ __launch_bounds__(512, 2) void dec_mfma(
    const u16* __restrict__ wsB,
    const float* __restrict__ bih, const float* __restrict__ bhh,
    const float* __restrict__ X, const float* __restrict__ z,
    const float* __restrict__ lin_w, const float* __restrict__ lin_b,
    float* __restrict__ pred)
{
  extern __shared__ char smem[];
  u16* Blds = (u16*)smem;
  u16* hA   = Blds + BLDS_U16;
  u16* xall = hA + HA_U16;
  u16* lwfc = xall + XALL_U16;
  const int p = blockIdx.x;
  const int b0 = blockIdx.y * 8;
  gru_body<54, true>(hA, xall, Blds, lwfc, wsB + (size_t)p*SER_STRIDE,
                     bih + p*768, bhh + p*768, X, z,
                     lin_w + p*256, lin_b + p, pred + p*3456, b0);
}

extern "C" void kernel_launch(void* const* d_in, const int* in_sizes, int n_in,
                              void* d_out, int out_size, void* d_ws, size_t ws_size,
                              hipStream_t stream) {
  const float* X        = (const float*)d_in[0];
  const float* eps      = (const float*)d_in[1];
  const float* Wih_enc  = (const float*)d_in[2];
  const float* Whh_enc  = (const float*)d_in[3];
  const float* bih_enc  = (const float*)d_in[4];
  const float* bhh_enc  = (const float*)d_in[5];
  const float* fc_mu_w  = (const float*)d_in[6];
  const float* fc_mu_b  = (const float*)d_in[7];
  const float* fc_std_w = (const float*)d_in[8];
  const float* fc_std_b = (const float*)d_in[9];
  const float* Wih_dec  = (const float*)d_in[10];
  const float* Whh_dec  = (const float*)d_in[11];
  const float* bih_dec  = (const float*)d_in[12];
  const float* bhh_dec  = (const float*)d_in[13];
  const float* lin_w    = (const float*)d_in[14];
  const float* lin_b    = (const float*)d_in[15];

  float* out    = (float*)d_out;
  float* pred   = out;              // [32][64][54][1] = 110592
  float* out_lv = out + 110592;     // [1][64][256]
  float* out_mu = out + 126976;     // [1][64][256]

  u16*   wsB = (u16*)d_ws;                                       // 33 * 221184 u16
  float* z   = (float*)((char*)d_ws + (size_t)33*SER_STRIDE*2);  // [64][256] fp32

  (void)hipFuncSetAttribute((const void*)enc_lat,
      hipFuncAttributeMaxDynamicSharedMemorySize, SMEM_BYTES);
  (void)hipFuncSetAttribute((const void*)dec_mfma,
      hipFuncAttributeMaxDynamicSharedMemorySize, SMEM_BYTES);

  pack_kernel<<<dim3(108, 33), 256, 0, stream>>>(Wih_dec, Whh_dec, Wih_enc, Whh_enc, wsB);
  enc_lat<<<dim3(1, 8), 512, SMEM_BYTES, stream>>>(
      wsB, bih_enc, bhh_enc, X,
      fc_mu_w, fc_mu_b, fc_std_w, fc_std_b, eps, z, out_lv, out_mu);
  dec_mfma<<<dim3(32, 8), 512, SMEM_BYTES, stream>>>(
      wsB, bih_dec, bhh_dec, X, z, lin_w, lin_b, pred);
}